// Round 13
// baseline (518.127 us; speedup 1.0000x reference)
//
#include <hip/hip_runtime.h>
#include <stdint.h>
#include <stddef.h>

// Problem constants (B,S,H,D fixed by the reference)
#define B_ 2
#define H_ 16
#define S_ 2048
#define D_ 64

#define TQ 32              // q-rows per MFMA tile
#define TK 256             // k cols per chunk
#define NW 4               // waves per block
#define BLK (NW*64)        // 256 threads
#define NBLK_R (32*32)     // 1024 blocks: 32 bh x 32 rects (20 compute + 12 masked)

typedef __attribute__((ext_vector_type(8))) short bf16x8;
typedef __attribute__((ext_vector_type(4))) float f32x4;

// f32 -> bf16 (round-to-nearest-even)
__device__ __forceinline__ unsigned short f2bf(float f) {
  union { float f; uint32_t u; } v; v.f = f;
  uint32_t r = v.u + 0x7FFFu + ((v.u >> 16) & 1u);
  return (unsigned short)(r >> 16);
}

// stage 256-row K chunk `kc` into ldsK (bf16, XOR-swizzled 8-elem granules)
__device__ __forceinline__ void stage_k(const f32x4* kp, unsigned short* ldsK,
                                        int b, int h, int kc, int tid) {
#pragma unroll
  for (int i = 0; i < 8; ++i) {
    const int g  = i * BLK + tid;
    const int kl = g >> 3;
    const int gd = g & 7;
    const size_t gb = (((size_t)b * S_ + (kc * TK + kl)) * H_ + h) * (D_ / 4) + gd * 2;
    f32x4 v0 = kp[gb];
    f32x4 v1 = kp[gb + 1];
    bf16x8 bv;
    bv[0] = (short)f2bf(v0.x); bv[1] = (short)f2bf(v0.y);
    bv[2] = (short)f2bf(v0.z); bv[3] = (short)f2bf(v0.w);
    bv[4] = (short)f2bf(v1.x); bv[5] = (short)f2bf(v1.y);
    bv[6] = (short)f2bf(v1.z); bv[7] = (short)f2bf(v1.w);
    const int idx = (kl * D_ + gd * 8) ^ ((kl & 7) << 3);
    *reinterpret_cast<bf16x8*>(&ldsK[idx]) = bv;
  }
}

// direct-from-global Q fragments (B-operand) for a 32-row q-tile at qb.
// Loaded ONCE per block and held in registers across all chunk passes.
// lane holds q = qb + qf*16 + colk, d = hh*32 + rg*8 + j  (pre-scaled 1/8)
__device__ __forceinline__ void load_qfr_g(const float* __restrict__ Qg,
                                           int b, int h, int qb,
                                           int colk, int rg, bf16x8 qfr[2][2]) {
#pragma unroll
  for (int qf = 0; qf < 2; ++qf) {
    const float* rowp = Qg + (((size_t)b * S_ + qb + qf * 16 + colk) * H_ + h) * D_;
#pragma unroll
    for (int hh = 0; hh < 2; ++hh) {
      const float* p = rowp + hh * 32 + rg * 8;
      f32x4 v0 = *reinterpret_cast<const f32x4*>(p);
      f32x4 v1 = *reinterpret_cast<const f32x4*>(p + 4);
      bf16x8 q8;
      q8[0] = (short)f2bf(v0.x * 0.125f); q8[1] = (short)f2bf(v0.y * 0.125f);
      q8[2] = (short)f2bf(v0.z * 0.125f); q8[3] = (short)f2bf(v0.w * 0.125f);
      q8[4] = (short)f2bf(v1.x * 0.125f); q8[5] = (short)f2bf(v1.y * 0.125f);
      q8[6] = (short)f2bf(v1.z * 0.125f); q8[7] = (short)f2bf(v1.w * 0.125f);
      qfr[qf][hh] = q8;
    }
  }
}

// per-wave whole-tile exp-sum for one 32x256 tile vs resident K chunk
// A=K (m=k), B=Q (n=q); D: col(lane&15)=q_local, row(rg*4+r)=k_local
__device__ __forceinline__ void sums_tile(const unsigned short* ldsK,
                                          const bf16x8 qfr[2][2],
                                          int qb, int kbase, int colk, int rg,
                                          float rsum[2]) {
#pragma unroll
  for (int kf = 0; kf < 16; ++kf) {
    const int krow = kf * 16 + colk;
    const int i0 = (krow * D_ + rg * 8) ^ ((krow & 7) << 3);
    const int i1 = (krow * D_ + 32 + rg * 8) ^ ((krow & 7) << 3);
    bf16x8 a0 = *reinterpret_cast<const bf16x8*>(&ldsK[i0]);
    bf16x8 a1 = *reinterpret_cast<const bf16x8*>(&ldsK[i1]);
#pragma unroll
    for (int qf = 0; qf < 2; ++qf) {
      f32x4 acc = (f32x4)0.0f;
      acc = __builtin_amdgcn_mfma_f32_16x16x32_bf16(a0, qfr[qf][0], acc, 0, 0, 0);
      acc = __builtin_amdgcn_mfma_f32_16x16x32_bf16(a1, qfr[qf][1], acc, 0, 0, 0);
      const int qq = qb + qf * 16 + colk;
#pragma unroll
      for (int r = 0; r < 4; ++r) {
        const int kk = kbase + kf * 16 + rg * 4 + r;
        rsum[qf] += (kk <= qq) ? __expf(acc[r]) : 0.f;
      }
    }
  }
}

// per-wave whole-tile recompute + scale + nt-store for one 32x256 tile
__device__ __forceinline__ void store_tile(const unsigned short* ldsK,
                                           const bf16x8 qfr[2][2],
                                           int qb, int kmin, const float rinv[2],
                                           float* __restrict__ outT,
                                           int colk, int rg) {
#pragma unroll
  for (int kf = 0; kf < 16; ++kf) {
    const int krow = kf * 16 + colk;
    const int i0 = (krow * D_ + rg * 8) ^ ((krow & 7) << 3);
    const int i1 = (krow * D_ + 32 + rg * 8) ^ ((krow & 7) << 3);
    bf16x8 a0 = *reinterpret_cast<const bf16x8*>(&ldsK[i0]);
    bf16x8 a1 = *reinterpret_cast<const bf16x8*>(&ldsK[i1]);
#pragma unroll
    for (int qf = 0; qf < 2; ++qf) {
      f32x4 acc = (f32x4)0.0f;
      acc = __builtin_amdgcn_mfma_f32_16x16x32_bf16(a0, qfr[qf][0], acc, 0, 0, 0);
      acc = __builtin_amdgcn_mfma_f32_16x16x32_bf16(a1, qfr[qf][1], acc, 0, 0, 0);
      const int qq = qb + qf * 16 + colk;
      f32x4 o;
#pragma unroll
      for (int r = 0; r < 4; ++r) {
        const int kk = kmin + kf * 16 + rg * 4 + r;
        o[r] = (kk <= qq) ? __expf(acc[r]) * rinv[qf] : 0.f;
      }
      __builtin_nontemporal_store(o, reinterpret_cast<f32x4*>(
          outT + (size_t)(qf * 16 + colk) * S_ + kf * 16 + rg * 4));
    }
  }
}

// =================== single fused kernel: self-sufficient rects ============
// Block (bh, qg, kc) owns output rect rows [512qg,+512) x cols [256kc,+256).
// Compute rects (kc <= 2qg+1): loop K chunks 0..2qg+1 (kc LAST -> resident
// for store), each wave owns 4 q-tiles end-to-end (Q in regs, sums in regs,
// reduce once, store). Masked rects: pure zero-fill. No workspace, no
// inter-block dependency, single launch.
__global__ __launch_bounds__(BLK, 4)
void attn_fused_v8(const float* __restrict__ Qg, const float* __restrict__ Kg,
                   float* __restrict__ Og) {
  __shared__ unsigned short ldsK[TK * D_];   // 32 KB (only LDS use)

  const int tid  = threadIdx.x;
  const int lane = tid & 63;
  const int w    = tid >> 6;
  const int colk = lane & 15;
  const int rg   = lane >> 4;

  int bid = (int)blockIdx.x;
  bid = (bid & 7) * (NBLK_R / 8) + (bid >> 3);     // bijective XCD swizzle
  const int bh  = bid >> 5;
  const int idx = bid & 31;                        // rect id (heavy-first)
  // rect table (arithmetic, no runtime-indexed arrays):
  //  0- 7: qg=3 kc=0..7 | 8-13: qg=2 kc=0..5 | 14-17: qg=1 kc=0..3
  // 18-25: qg=0 kc=0..7 (kc>=2 masked) | 26-29: qg=1 kc=4..7 (masked)
  // 30-31: qg=2 kc=6..7 (masked)
  int qg, kc;
  if      (idx <  8) { qg = 3; kc = idx; }
  else if (idx < 14) { qg = 2; kc = idx - 8; }
  else if (idx < 18) { qg = 1; kc = idx - 14; }
  else if (idx < 26) { qg = 0; kc = idx - 18; }
  else if (idx < 30) { qg = 1; kc = idx - 22; }
  else               { qg = 2; kc = idx - 24; }
  const int b = bh >> 4, h = bh & (H_ - 1);
  const int kmin = kc * TK;
  const int row0 = qg * 512;

  float* outB = Og + (size_t)bh * S_ * S_;

  if (kc > 2 * qg + 1) {
    // fully-masked rect: stream zeros, exit
    f32x4 z = {0.f, 0.f, 0.f, 0.f};
#pragma unroll 4
    for (int it = 0; it < 128; ++it) {
      const int g = it * BLK + tid;
      const int row = row0 + (g >> 6);
      const int cg = g & 63;
      __builtin_nontemporal_store(z, reinterpret_cast<f32x4*>(
          outB + (size_t)row * S_ + kmin + cg * 4));
    }
    return;
  }

  // wave w owns tiles i = w + 4j, j=0..3
  int qb[4]; int top[4]; bool live[4];
#pragma unroll
  for (int j = 0; j < 4; ++j) {
    qb[j]  = row0 + (w + 4 * j) * TQ;
    live[j] = (qb[j] >= kmin);                     // tile rows unmasked?
    top[j] = (qb[j] + 31) >> 8;                    // last causal chunk
  }

  // zero-fill this wave's masked-prefix tiles (overlaps later staging)
  {
    f32x4 z = {0.f, 0.f, 0.f, 0.f};
#pragma unroll
    for (int j = 0; j < 4; ++j)
      if (!live[j]) {
        float* tp = outB + (size_t)qb[j] * S_ + kmin;
#pragma unroll 4
        for (int it = 0; it < 32; ++it)
          __builtin_nontemporal_store(z, reinterpret_cast<f32x4*>(
              tp + (size_t)it * S_ + lane * 4));
      }
  }

  // Q fragments for live tiles: loaded ONCE, held in regs across all chunks
  bf16x8 qfr[4][2][2];
#pragma unroll
  for (int j = 0; j < 4; ++j)
    if (live[j]) load_qfr_g(Qg, b, h, qb[j], colk, rg, qfr[j]);

  const f32x4* kp = reinterpret_cast<const f32x4*>(Kg);
  float rsum[4][2] = {{0.f,0.f},{0.f,0.f},{0.f,0.f},{0.f,0.f}};

  // chunk loop: c in {0..2qg+1} with kc moved LAST (K_kc stays resident)
  const int NC = 2 * qg + 2;
  for (int cc = 0; cc < NC; ++cc) {
    const int c = (cc == NC - 1) ? kc : (cc < kc ? cc : cc + 1);
    __syncthreads();                               // prev chunk consumed
    stage_k(kp, ldsK, b, h, c, tid);
    __syncthreads();                               // chunk resident
#pragma unroll
    for (int j = 0; j < 4; ++j)
      if (live[j] && c <= top[j])
        sums_tile(ldsK, qfr[j], qb[j], c * TK, colk, rg, rsum[j]);
  }

  // reduce per-lane partials across rg (lane bits 4,5); every lane gets sum
  float rinv[4][2];
#pragma unroll
  for (int j = 0; j < 4; ++j)
#pragma unroll
    for (int qf = 0; qf < 2; ++qf) {
      float v = rsum[j][qf];
      v += __shfl_xor(v, 16);
      v += __shfl_xor(v, 32);
      rinv[j][qf] = 1.0f / v;
    }

  // store pass: K_kc resident (last staged); no further barriers needed
#pragma unroll
  for (int j = 0; j < 4; ++j)
    if (live[j])
      store_tile(ldsK, qfr[j], qb[j], kmin, rinv[j],
                 outB + (size_t)qb[j] * S_ + kmin, colk, rg);
}

extern "C" void kernel_launch(void* const* d_in, const int* in_sizes, int n_in,
                              void* d_out, int out_size, void* d_ws, size_t ws_size,
                              hipStream_t stream) {
  const float* Qg = (const float*)d_in[0];
  const float* Kg = (const float*)d_in[1];
  // d_in[2] is the causal mask; tril by construction -> k<=q predicate
  float* Og = (float*)d_out;
  attn_fused_v8<<<dim3(NBLK_R), dim3(BLK), 0, stream>>>(Qg, Kg, Og);
}

// Round 14
// 154.374 us; speedup vs baseline: 3.3563x; 3.3563x over previous
//
#include <hip/hip_runtime.h>
#include <stdint.h>
#include <stddef.h>

// Problem constants (B,S,H,D fixed by the reference)
#define B_ 2
#define H_ 16
#define S_ 2048
#define D_ 64

#define TQ 32              // q-rows per MFMA tile
#define TK 256             // k rows per resident chunk
#define NW 4               // waves per block
#define BLK (NW*64)        // 256 threads
#define NQT (S_/TQ)        // 64 q-tiles per (b,h)
#define NBLK_F (B_*H_*NQT) // fused-fallback grid
#define NBLK_S (32*36)     // sums grid: 32 bh x sum_kc(8-kc)=36
#define NBLK_W (32*8*4)    // store grid: bh x kc x qg

typedef __attribute__((ext_vector_type(8))) short bf16x8;
typedef __attribute__((ext_vector_type(4))) float f32x4;

// f32 -> bf16 (round-to-nearest-even)
__device__ __forceinline__ unsigned short f2bf(float f) {
  union { float f; uint32_t u; } v; v.f = f;
  uint32_t r = v.u + 0x7FFFu + ((v.u >> 16) & 1u);
  return (unsigned short)(r >> 16);
}

// stage 256-row K chunk `kc` into ldsK (bf16, XOR-swizzled 8-elem granules)
__device__ __forceinline__ void stage_k(const f32x4* kp, unsigned short* ldsK,
                                        int b, int h, int kc, int tid) {
#pragma unroll
  for (int i = 0; i < 8; ++i) {
    const int g  = i * BLK + tid;
    const int kl = g >> 3;
    const int gd = g & 7;
    const size_t gb = (((size_t)b * S_ + (kc * TK + kl)) * H_ + h) * (D_ / 4) + gd * 2;
    f32x4 v0 = kp[gb];
    f32x4 v1 = kp[gb + 1];
    bf16x8 bv;
    bv[0] = (short)f2bf(v0.x); bv[1] = (short)f2bf(v0.y);
    bv[2] = (short)f2bf(v0.z); bv[3] = (short)f2bf(v0.w);
    bv[4] = (short)f2bf(v1.x); bv[5] = (short)f2bf(v1.y);
    bv[6] = (short)f2bf(v1.z); bv[7] = (short)f2bf(v1.w);
    const int idx = (kl * D_ + gd * 8) ^ ((kl & 7) << 3);
    *reinterpret_cast<bf16x8*>(&ldsK[idx]) = bv;
  }
}

// stage 32-row Q tile into LDS (pre-scaled 1/8 = 1/sqrt(D))
__device__ __forceinline__ void stage_q(const f32x4* qp, unsigned short (*ldsQ)[72],
                                        int b, int h, int qb, int tid) {
#pragma unroll
  for (int i = 0; i < 2; ++i) {
    const int g   = i * BLK + tid;
    const int row = g >> 4;
    const int d4  = g & 15;
    f32x4 v = qp[(((size_t)b * S_ + (qb + row)) * H_ + h) * (D_ / 4) + d4];
    unsigned short* dst = &ldsQ[row][d4 * 4];
    dst[0] = f2bf(v.x * 0.125f);
    dst[1] = f2bf(v.y * 0.125f);
    dst[2] = f2bf(v.z * 0.125f);
    dst[3] = f2bf(v.w * 0.125f);
  }
}

// T14 split staging: issue global loads early...
struct QPre { f32x4 a, b; };
__device__ __forceinline__ QPre qpre_load(const f32x4* qp, int b, int h, int qb, int tid) {
  QPre r;
  {
    const int g = tid;            // half 0
    r.a = qp[(((size_t)b * S_ + (qb + (g >> 4))) * H_ + h) * (D_ / 4) + (g & 15)];
  }
  {
    const int g = BLK + tid;      // half 1
    r.b = qp[(((size_t)b * S_ + (qb + (g >> 4))) * H_ + h) * (D_ / 4) + (g & 15)];
  }
  return r;
}
// ...convert + LDS-write late (after the barrier)
__device__ __forceinline__ void qpre_write(unsigned short (*ldsQ)[72], const QPre& p, int tid) {
#pragma unroll
  for (int i = 0; i < 2; ++i) {
    const int g   = i * BLK + tid;
    const int row = g >> 4;
    const int d4  = g & 15;
    const f32x4 v = i ? p.b : p.a;
    unsigned short* dst = &ldsQ[row][d4 * 4];
    dst[0] = f2bf(v.x * 0.125f);
    dst[1] = f2bf(v.y * 0.125f);
    dst[2] = f2bf(v.z * 0.125f);
    dst[3] = f2bf(v.w * 0.125f);
  }
}

__device__ __forceinline__ void load_qfr(const unsigned short (*ldsQ)[72],
                                         bf16x8 qfr[2][2], int colk, int rg) {
#pragma unroll
  for (int qf = 0; qf < 2; ++qf)
#pragma unroll
    for (int hh = 0; hh < 2; ++hh)
      qfr[qf][hh] = *reinterpret_cast<const bf16x8*>(&ldsQ[qf * 16 + colk][hh * 32 + rg * 8]);
}

// A-operand = K (m = k), B-operand = Q (n = q)
// D: col(lane&15) = q_local, row(rg*4+reg) = k_local
__device__ __forceinline__ void mfma_tile(const unsigned short* ldsK,
                                          const bf16x8 qfr[2][2],
                                          f32x4 acc[4][2], int w, int colk, int rg) {
#pragma unroll
  for (int kf = 0; kf < 4; ++kf) {
    const int krow = w * 64 + kf * 16 + colk;
    const int i0 = (krow * D_ + rg * 8) ^ ((krow & 7) << 3);
    const int i1 = (krow * D_ + 32 + rg * 8) ^ ((krow & 7) << 3);
    bf16x8 a0 = *reinterpret_cast<const bf16x8*>(&ldsK[i0]);
    bf16x8 a1 = *reinterpret_cast<const bf16x8*>(&ldsK[i1]);
#pragma unroll
    for (int qf = 0; qf < 2; ++qf) {
      acc[kf][qf] = __builtin_amdgcn_mfma_f32_16x16x32_bf16(a0, qfr[qf][0], acc[kf][qf], 0, 0, 0);
      acc[kf][qf] = __builtin_amdgcn_mfma_f32_16x16x32_bf16(a1, qfr[qf][1], acc[kf][qf], 0, 0, 0);
    }
  }
}

// ---------------- kernel S: per-(kc,row) partial softmax denominators ------
// (R4-proven; best measured S variant)
__global__ __launch_bounds__(BLK, 4)
void attn_sums_v4(const float* __restrict__ Qg, const float* __restrict__ Kg,
                  float* __restrict__ wsPart) {
  __shared__ unsigned short ldsK[TK * D_];
  __shared__ unsigned short ldsQ[TQ][72];
  __shared__ float ldsSum[NW][2][16];

  const int tid  = threadIdx.x;
  const int lane = tid & 63;
  const int w    = tid >> 6;
  const int colk = lane & 15;
  const int rg   = lane >> 4;

  int bid = (int)blockIdx.x;
  bid = (bid & 7) * (NBLK_S / 8) + (bid >> 3);     // bijective XCD swizzle
  const int bh = bid / 36;
  int j = bid - bh * 36;
  int kc = 0, base = 0;
  while (j >= base + (8 - kc)) { base += 8 - kc; ++kc; }
  const int ci = j - base;
  const int qt0 = kc * 8 + ci * 8;
  const int b = bh >> 4, h = bh & (H_ - 1);

  const f32x4* qp = reinterpret_cast<const f32x4*>(Qg);
  const f32x4* kp = reinterpret_cast<const f32x4*>(Kg);

  stage_k(kp, ldsK, b, h, kc, tid);

  for (int i = 0; i < 8; ++i) {
    const int qt = qt0 + i;
    const int qb = qt * TQ;
    __syncthreads();
    stage_q(qp, ldsQ, b, h, qb, tid);
    __syncthreads();
    bf16x8 qfr[2][2];
    load_qfr(ldsQ, qfr, colk, rg);
    f32x4 acc[4][2];
#pragma unroll
    for (int kf = 0; kf < 4; ++kf)
#pragma unroll
      for (int qf = 0; qf < 2; ++qf) acc[kf][qf] = (f32x4)0.0f;
    mfma_tile(ldsK, qfr, acc, w, colk, rg);

    float rsum[2] = {0.f, 0.f};
#pragma unroll
    for (int kf = 0; kf < 4; ++kf)
#pragma unroll
      for (int qf = 0; qf < 2; ++qf)
#pragma unroll
        for (int r = 0; r < 4; ++r) {
          const int kk = kc * TK + w * 64 + kf * 16 + rg * 4 + r;
          const int qq = qb + qf * 16 + colk;
          rsum[qf] += (kk <= qq) ? __expf(acc[kf][qf][r]) : 0.f;
        }
#pragma unroll
    for (int qf = 0; qf < 2; ++qf) {
      float v = rsum[qf];
      v += __shfl_xor(v, 16);
      v += __shfl_xor(v, 32);
      rsum[qf] = v;
    }
    if (rg == 0) { ldsSum[w][0][colk] = rsum[0]; ldsSum[w][1][colk] = rsum[1]; }
    __syncthreads();
    if (tid < 32) {
      const int qf = tid >> 4, ck = tid & 15;
      const float s = ldsSum[0][qf][ck] + ldsSum[1][qf][ck] +
                      ldsSum[2][qf][ck] + ldsSum[3][qf][ck];
      wsPart[((size_t)bh * 8 + kc) * S_ + qb + tid] = s;
    }
  }
}

// ---------------- kernel W v6 (R8-proven): drain-free store loop -----------
__global__ __launch_bounds__(BLK, 4)
void attn_store_v6(const float* __restrict__ Qg, const float* __restrict__ Kg,
                   const float* __restrict__ wsPart, float* __restrict__ Og) {
  __shared__ unsigned short ldsK[TK * D_];   // 32 KB
  __shared__ unsigned short ldsQ[TQ][72];    // 4.5 KB (single buffer)
  __shared__ float rinvL[512];               // 2 KB

  const int tid  = threadIdx.x;
  const int lane = tid & 63;
  const int w    = tid >> 6;
  const int colk = lane & 15;
  const int rg   = lane >> 4;

  int bid = (int)blockIdx.x;
  bid = (bid & 7) * (NBLK_W / 8) + (bid >> 3);     // bijective XCD swizzle
  const int bh = bid >> 5;
  const int r5 = bid & 31;
  const int kc = r5 >> 2;
  const int qg = r5 & 3;
  const int b = bh >> 4, h = bh & (H_ - 1);
  const int kmin = kc * TK;
  const int row0 = qg * 512;

  // fully-masked rectangle: stream zeros (nt), exit
  if (kmin > row0 + 511) {
    f32x4 z = {0.f, 0.f, 0.f, 0.f};
#pragma unroll 4
    for (int it = 0; it < 128; ++it) {
      const int g = it * BLK + tid;
      const int row = row0 + (g >> 6);
      const int cg = g & 63;
      __builtin_nontemporal_store(z, reinterpret_cast<f32x4*>(
          Og + ((size_t)bh * S_ + row) * S_ + kmin + cg * 4));
    }
    return;
  }

  const f32x4* qp = reinterpret_cast<const f32x4*>(Qg);
  const f32x4* kp = reinterpret_cast<const f32x4*>(Kg);

  // first unmasked tile index: kmin-row0 is 0 or 256 here -> i0 in {0, 8}
  const int i0 = (kmin > row0) ? ((kmin - row0) >> 5) : 0;

  // masked tile prefix: zero-fill now (overlaps the K-stage reads below)
  if (i0 > 0) {
    f32x4 z = {0.f, 0.f, 0.f, 0.f};
#pragma unroll 4
    for (int it = 0; it < 64; ++it) {              // 256 rows x 256 cols
      const int g = it * BLK + tid;
      const int row = row0 + (g >> 6);
      const int cg = g & 63;
      __builtin_nontemporal_store(z, reinterpret_cast<f32x4*>(
          Og + ((size_t)bh * S_ + row) * S_ + kmin + cg * 4));
    }
  }

  stage_k(kp, ldsK, b, h, kc, tid);

  // 1/rowsum for this block's 512 rows (only rows >= kmin read later)
  for (int lr = tid; lr < 512; lr += BLK) {
    const int q = row0 + lr;
    if (q >= kmin) {
      float s = 0.f;
      const int top = q >> 8;
      for (int c2 = 0; c2 <= top; ++c2)
        s += wsPart[((size_t)bh * 8 + c2) * S_ + q];
      rinvL[lr] = 1.0f / s;
    }
  }

  stage_q(qp, ldsQ, b, h, row0 + i0 * TQ, tid);    // tile i0 into LDS
  __syncthreads();                                 // ONE full drain (prologue)

  QPre pre;
  if (i0 + 1 < 16) pre = qpre_load(qp, b, h, row0 + (i0 + 1) * TQ, tid);

  for (int i = i0; i < 16; ++i) {
    const int qb = row0 + i * TQ;
    float* outT = Og + ((size_t)bh * S_ + qb) * S_ + kmin;

    bf16x8 qfr[2][2];
    load_qfr(ldsQ, qfr, colk, rg);                 // ds_read_b128 x4
    asm volatile("s_waitcnt lgkmcnt(0)" ::: "memory");
    __builtin_amdgcn_sched_barrier(0);
    __builtin_amdgcn_s_barrier();                  // all waves' reads done

    if (i + 1 < 16) {
      qpre_write(ldsQ, pre, tid);                  // tile i+1 -> LDS (late write)
      if (i + 2 < 16) pre = qpre_load(qp, b, h, row0 + (i + 2) * TQ, tid);
      asm volatile("s_waitcnt lgkmcnt(0)" ::: "memory");
    }
    __builtin_amdgcn_s_barrier();                  // buf ready for next iter

    f32x4 acc[4][2];
#pragma unroll
    for (int kf = 0; kf < 4; ++kf)
#pragma unroll
      for (int qf = 0; qf < 2; ++qf) acc[kf][qf] = (f32x4)0.0f;
    mfma_tile(ldsK, qfr, acc, w, colk, rg);

#pragma unroll
    for (int kf = 0; kf < 4; ++kf)
#pragma unroll
      for (int qf = 0; qf < 2; ++qf) {
        const int qq = qb + qf * 16 + colk;
        const float ri = rinvL[i * 32 + qf * 16 + colk];
        f32x4 o;
#pragma unroll
        for (int r = 0; r < 4; ++r) {
          const int kk = kmin + w * 64 + kf * 16 + rg * 4 + r;
          o[r] = (kk <= qq) ? __expf(acc[kf][qf][r]) * ri : 0.f;
        }
        __builtin_nontemporal_store(o, reinterpret_cast<f32x4*>(
            outT + (size_t)(qf * 16 + colk) * S_ + w * 64 + kf * 16 + rg * 4));
      }
    // no vmcnt drain — stores stay in flight across iterations
  }
}

// ---------------- fallback: fused two-pass (if ws too small) ---------------
__global__ __launch_bounds__(BLK, 4)
void attn_weights_fused(const float* __restrict__ Qg, const float* __restrict__ Kg,
                        float* __restrict__ Og) {
  __shared__ unsigned short ldsK[TK * D_];
  __shared__ unsigned short ldsQ[TQ][72];
  __shared__ float ldsSum[NW][2][16];

  const int tid  = threadIdx.x;
  const int lane = tid & 63;
  const int w    = tid >> 6;
  const int colk = lane & 15;
  const int rg   = lane >> 4;

  int bid = (int)blockIdx.x;
  bid = (bid & 7) * (NBLK_F / 8) + (bid >> 3);
  const int qt = bid & (NQT - 1);
  const int bh = bid >> 6;
  const int h  = bh & (H_ - 1);
  const int b  = bh >> 4;
  const int qb = qt * TQ;
  const int tmax = qb >> 8;

  float* outp = Og + ((size_t)bh * S_ + qb) * S_;
  {
    const int row = tid >> 3;
    f32x4 z = {0.f, 0.f, 0.f, 0.f};
    float* rp = outp + (size_t)row * S_;
    for (int c = (tmax + 1) * (TK / 4) + (tid & 7); c < S_ / 4; c += 8)
      *reinterpret_cast<f32x4*>(rp + c * 4) = z;
  }
  const f32x4* qp = reinterpret_cast<const f32x4*>(Qg);
  const f32x4* kp = reinterpret_cast<const f32x4*>(Kg);
  stage_q(qp, ldsQ, b, h, qb, tid);
  __syncthreads();
  bf16x8 qfr[2][2];
  load_qfr(ldsQ, qfr, colk, rg);
  float rsum[2] = {0.f, 0.f};
  for (int t = 0; t <= tmax; ++t) {
    stage_k(kp, ldsK, b, h, t, tid);
    __syncthreads();
    f32x4 acc[4][2];
#pragma unroll
    for (int kf = 0; kf < 4; ++kf)
#pragma unroll
      for (int qf = 0; qf < 2; ++qf) acc[kf][qf] = (f32x4)0.0f;
    mfma_tile(ldsK, qfr, acc, w, colk, rg);
#pragma unroll
    for (int kf = 0; kf < 4; ++kf)
#pragma unroll
      for (int qf = 0; qf < 2; ++qf)
#pragma unroll
        for (int r = 0; r < 4; ++r) {
          const int kk = t * TK + w * 64 + kf * 16 + rg * 4 + r;
          const int qq = qb + qf * 16 + colk;
          rsum[qf] += (kk <= qq) ? __expf(acc[kf][qf][r]) : 0.f;
        }
    __syncthreads();
  }
#pragma unroll
  for (int qf = 0; qf < 2; ++qf) {
    float v = rsum[qf];
    v += __shfl_xor(v, 16);
    v += __shfl_xor(v, 32);
    rsum[qf] = v;
  }
  if (rg == 0) { ldsSum[w][0][colk] = rsum[0]; ldsSum[w][1][colk] = rsum[1]; }
  __syncthreads();
  float rinv[2];
#pragma unroll
  for (int qf = 0; qf < 2; ++qf)
    rinv[qf] = 1.0f / (ldsSum[0][qf][colk] + ldsSum[1][qf][colk] +
                       ldsSum[2][qf][colk] + ldsSum[3][qf][colk]);
  for (int t = 0; t <= tmax; ++t) {
    stage_k(kp, ldsK, b, h, t, tid);
    __syncthreads();
    f32x4 acc[4][2];
#pragma unroll
    for (int kf = 0; kf < 4; ++kf)
#pragma unroll
      for (int qf = 0; qf < 2; ++qf) acc[kf][qf] = (f32x4)0.0f;
    mfma_tile(ldsK, qfr, acc, w, colk, rg);
#pragma unroll
    for (int kf = 0; kf < 4; ++kf)
#pragma unroll
      for (int qf = 0; qf < 2; ++qf) {
        f32x4 o;
#pragma unroll
        for (int r = 0; r < 4; ++r) {
          const int kk = t * TK + w * 64 + kf * 16 + rg * 4 + r;
          const int qq = qb + qf * 16 + colk;
          o[r] = (kk <= qq) ? __expf(acc[kf][qf][r]) * rinv[qf] : 0.f;
        }
        *reinterpret_cast<f32x4*>(outp + (size_t)(qf * 16 + colk) * S_ +
                                  t * TK + w * 64 + kf * 16 + rg * 4) = o;
      }
    __syncthreads();
  }
}

extern "C" void kernel_launch(void* const* d_in, const int* in_sizes, int n_in,
                              void* d_out, int out_size, void* d_ws, size_t ws_size,
                              hipStream_t stream) {
  const float* Qg = (const float*)d_in[0];
  const float* Kg = (const float*)d_in[1];
  // d_in[2] is the causal mask; tril by construction -> k<=q predicate
  float* Og = (float*)d_out;
  const size_t need = (size_t)32 * 8 * S_ * sizeof(float);   // 2 MB partials
  if (ws_size >= need) {
    float* wsPart = (float*)d_ws;
    attn_sums_v4 <<<dim3(NBLK_S), dim3(BLK), 0, stream>>>(Qg, Kg, wsPart);
    attn_store_v6<<<dim3(NBLK_W), dim3(BLK), 0, stream>>>(Qg, Kg, wsPart, Og);
  } else {
    attn_weights_fused<<<dim3(NBLK_F), dim3(BLK), 0, stream>>>(Qg, Kg, Og);
  }
}